// Round 1
// baseline (98.197 us; speedup 1.0000x reference)
//
#include <hip/hip_runtime.h>
#include <stdint.h>

typedef __bf16 bf16;
typedef bf16 bf16x8 __attribute__((ext_vector_type(8)));
typedef bf16 bf16x4 __attribute__((ext_vector_type(4)));
typedef float f32x4 __attribute__((ext_vector_type(4)));

#define NB 8
#define NS 1024
#define NC 512
#define NH 8
#define ND 64

// q pre-scale: dim_head^-0.5 * log2(e) so attention uses exp2 directly
#define QSCALE 0.18033688011f

// ---------------- 1) BN(eval) + transpose: x[b][c][s] -> t[b][s][c] bf16 ----
__global__ __launch_bounds__(256) void bn_tr_kernel(
    const float* __restrict__ x, const float* __restrict__ gam,
    const float* __restrict__ bet, const float* __restrict__ mu,
    const float* __restrict__ var, bf16* __restrict__ t) {
  __shared__ float tile[32][33];
  const int b = blockIdx.z, c0 = blockIdx.y * 32, s0 = blockIdx.x * 32;
  const int tx = threadIdx.x, sj = tx & 31, ci = tx >> 5;
#pragma unroll
  for (int kk = 0; kk < 4; ++kk) {
    const int c = c0 + ci + (kk << 3);
    const float sc = gam[c] * rsqrtf(var[c] + 1e-5f);
    const float sh = bet[c] - mu[c] * sc;
    tile[ci + (kk << 3)][sj] = x[(size_t)(b * NC + c) * NS + s0 + sj] * sc + sh;
  }
  __syncthreads();
#pragma unroll
  for (int kk = 0; kk < 4; ++kk) {
    const int s = s0 + ci + (kk << 3);
    t[(size_t)(b * NS + s) * NC + c0 + sj] = (bf16)tile[sj][ci + (kk << 3)];
  }
}

// ---------------- 2) weights f32 -> bf16 ------------------------------------
__global__ __launch_bounds__(256) void wconv_kernel(
    const float* __restrict__ wq, const float* __restrict__ wk,
    const float* __restrict__ wv, const float* __restrict__ wo,
    bf16* __restrict__ wqb, bf16* __restrict__ wkb, bf16* __restrict__ wvb,
    bf16* __restrict__ wob) {
  const int i = blockIdx.x * 256 + threadIdx.x;
  wqb[i] = (bf16)wq[i];
  wkb[i] = (bf16)wk[i];
  wvb[i] = (bf16)wv[i];
  wob[i] = (bf16)wo[i];
}

// ---------------- 3) QKV GEMM: C[m,n] = sum_k t[m,k]*W[n,k] + b[n] ----------
// m = (b,s) over 8192, n = 0..1535 picks {wq,wk,wv}; out layout [B][H][S][D]
__global__ __launch_bounds__(256) void gemm_qkv_kernel(
    const bf16* __restrict__ t, const bf16* __restrict__ wqb,
    const bf16* __restrict__ wkb, const bf16* __restrict__ wvb,
    const float* __restrict__ bq, const float* __restrict__ bk,
    const float* __restrict__ bv, bf16* __restrict__ qo, bf16* __restrict__ ko,
    bf16* __restrict__ vo) {
  __shared__ __align__(16) bf16 As[128 * 32];
  __shared__ __align__(16) bf16 Bs[128 * 32];
  const int tid = threadIdx.x;
  const int m0 = blockIdx.x * 128, n0 = blockIdx.y * 128;
  const int wsel = n0 >> 9;
  const bf16* W = (wsel == 0) ? wqb : (wsel == 1 ? wkb : wvb);
  const float* bias = (wsel == 0) ? bq : (wsel == 1 ? bk : bv);
  bf16* outp = (wsel == 0) ? qo : (wsel == 1 ? ko : vo);
  const int nb = n0 & 511;
  const int w = tid >> 6, lane = tid & 63, l15 = lane & 15, l4 = lane >> 4;
  const int wm = (w >> 1) << 6, wn = (w & 1) << 6;
  f32x4 acc[4][4] = {};
  for (int k0 = 0; k0 < 512; k0 += 32) {
    __syncthreads();
#pragma unroll
    for (int i = 0; i < 2; ++i) {
      const int c = i * 256 + tid, row = c >> 2, slot = c & 3;
      const int ds = (slot ^ ((row >> 1) & 3)) << 3;
      *(int4*)(&As[row * 32 + ds]) =
          *(const int4*)(&t[(size_t)(m0 + row) * 512 + k0 + slot * 8]);
      *(int4*)(&Bs[row * 32 + ds]) =
          *(const int4*)(&W[(size_t)(nb + row) * 512 + k0 + slot * 8]);
    }
    __syncthreads();
    bf16x8 af[4], bfv[4];
#pragma unroll
    for (int mi = 0; mi < 4; ++mi) {
      const int row = wm + mi * 16 + l15;
      af[mi] = *(const bf16x8*)(&As[row * 32 + ((l4 ^ ((row >> 1) & 3)) << 3)]);
    }
#pragma unroll
    for (int ni = 0; ni < 4; ++ni) {
      const int row = wn + ni * 16 + l15;
      bfv[ni] = *(const bf16x8*)(&Bs[row * 32 + ((l4 ^ ((row >> 1) & 3)) << 3)]);
    }
#pragma unroll
    for (int mi = 0; mi < 4; ++mi)
#pragma unroll
      for (int ni = 0; ni < 4; ++ni)
        acc[mi][ni] = __builtin_amdgcn_mfma_f32_16x16x32_bf16(af[mi], bfv[ni],
                                                              acc[mi][ni], 0, 0, 0);
  }
  const int bidx = m0 >> 10;
  const int sbase = (m0 & 1023) + wm + (l4 << 2);
  const bool isq = (wsel == 0);
#pragma unroll
  for (int ni = 0; ni < 4; ++ni) {
    const int nn = nb + wn + ni * 16 + l15;
    const int hh = nn >> 6, dd = nn & 63;
    const float bsv = bias[nn];
    bf16* obase = outp + (size_t)(bidx * NH + hh) * (NS * ND) + dd;
#pragma unroll
    for (int mi = 0; mi < 4; ++mi) {
#pragma unroll
      for (int r = 0; r < 4; ++r) {
        float val = acc[mi][ni][r] + bsv;
        if (isq) val *= QSCALE;
        obase[(size_t)(sbase + mi * 16 + r) * ND] = (bf16)val;
      }
    }
  }
}

// ---------------- 4) V transpose per (b,h): [S][D] -> [D][S] ----------------
__global__ __launch_bounds__(256) void vtr_kernel(const bf16* __restrict__ v,
                                                  bf16* __restrict__ vt) {
  __shared__ bf16 tile[64][72];
  const int bh = blockIdx.y, s0 = blockIdx.x * 64;
  const int tx = threadIdx.x;
  const bf16* src = v + ((size_t)bh * NS + s0) * ND;
  bf16* dst = vt + (size_t)bh * ND * NS + s0;
#pragma unroll
  for (int it = 0; it < 2; ++it) {
    const int sr = (tx >> 3) + it * 32, d0 = (tx & 7) * 8;
    const bf16x8 val = *(const bf16x8*)(&src[sr * ND + d0]);
#pragma unroll
    for (int i = 0; i < 8; ++i) tile[d0 + i][sr] = val[i];
  }
  __syncthreads();
#pragma unroll
  for (int it = 0; it < 2; ++it) {
    const int dr = (tx >> 3) + it * 32, si = (tx & 7) * 8;
    bf16x8 val;
#pragma unroll
    for (int i = 0; i < 8; ++i) val[i] = tile[dr][si + i];
    *(bf16x8*)(&dst[(size_t)dr * NS + si]) = val;
  }
}

// ---------------- 5) flash attention ----------------------------------------
// grid (S/64, B*H). block = 4 waves; wave w owns q-rows [w*16, w*16+16).
// Swapped QK^T: st = mfma(Kfrag, Qfrag) -> lane holds 16 scores of ONE q-row.
__global__ __launch_bounds__(256) void attn_kernel(const bf16* __restrict__ qg,
                                                   const bf16* __restrict__ kg,
                                                   const bf16* __restrict__ vtg,
                                                   bf16* __restrict__ og) {
  __shared__ __align__(16) bf16 Qs[64 * 64];
  __shared__ __align__(16) bf16 Ks[64 * 64];
  __shared__ __align__(16) bf16 Vs[64 * 64];
  __shared__ __align__(16) bf16 Ps[4][16 * 64];
  const int bh = blockIdx.y, q0 = blockIdx.x * 64;
  const int tid = threadIdx.x, w = tid >> 6, lane = tid & 63;
  const int l15 = lane & 15, l4 = lane >> 4;
  const bf16* Qp = qg + ((size_t)bh * NS + q0) * ND;
  const bf16* Kp = kg + (size_t)bh * NS * ND;
  const bf16* Vp = vtg + (size_t)bh * ND * NS;

  // stage Q [64][64], XOR-address-swizzled (16B slot ^ row&7)
#pragma unroll
  for (int it = 0; it < 2; ++it) {
    const int c = it * 256 + tid, row = c >> 3, slot = c & 7;
    *(int4*)(&Qs[row * 64 + ((slot ^ (row & 7)) << 3)]) =
        *(const int4*)(&Qp[row * 64 + slot * 8]);
  }
  __syncthreads();
  bf16x8 qf[2];
#pragma unroll
  for (int kk = 0; kk < 2; ++kk) {
    const int row = w * 16 + l15;
    qf[kk] = *(const bf16x8*)(&Qs[row * 64 + ((((kk << 2) + l4) ^ (row & 7)) << 3)]);
  }

  f32x4 oacc[4] = {};
  float mrun = -1e30f, lrun = 0.f;

  for (int kv0 = 0; kv0 < NS; kv0 += 64) {
    __syncthreads();
#pragma unroll
    for (int it = 0; it < 2; ++it) {
      const int c = it * 256 + tid, row = c >> 3, slot = c & 7;
      const int ds = (slot ^ (row & 7)) << 3;
      *(int4*)(&Ks[row * 64 + ds]) =
          *(const int4*)(&Kp[(size_t)(kv0 + row) * ND + slot * 8]);
      *(int4*)(&Vs[row * 64 + ds]) =
          *(const int4*)(&Vp[(size_t)row * NS + kv0 + slot * 8]);
    }
    __syncthreads();
    // S^T tiles: st[rt][r] = score(kv = rt*16 + l4*4 + r, q = l15)
    f32x4 st[4];
#pragma unroll
    for (int rt = 0; rt < 4; ++rt) {
      const int row = rt * 16 + l15;
      const bf16x8 a0 = *(const bf16x8*)(&Ks[row * 64 + ((l4 ^ (row & 7)) << 3)]);
      const bf16x8 a1 =
          *(const bf16x8*)(&Ks[row * 64 + (((4 + l4) ^ (row & 7)) << 3)]);
      f32x4 z = {0.f, 0.f, 0.f, 0.f};
      z = __builtin_amdgcn_mfma_f32_16x16x32_bf16(a0, qf[0], z, 0, 0, 0);
      st[rt] = __builtin_amdgcn_mfma_f32_16x16x32_bf16(a1, qf[1], z, 0, 0, 0);
    }
    // online softmax for q-row l15 (16 in-lane values + xor16/32 across l4)
    float pm = -1e30f;
#pragma unroll
    for (int rt = 0; rt < 4; ++rt)
#pragma unroll
      for (int r = 0; r < 4; ++r) pm = fmaxf(pm, st[rt][r]);
    pm = fmaxf(pm, __shfl_xor(pm, 16));
    pm = fmaxf(pm, __shfl_xor(pm, 32));
    const float mnew = fmaxf(mrun, pm);
    const float alpha = exp2f(mrun - mnew);
    float rs = 0.f;
#pragma unroll
    for (int rt = 0; rt < 4; ++rt) {
      bf16x4 pk;
#pragma unroll
      for (int r = 0; r < 4; ++r) {
        const float p = exp2f(st[rt][r] - mnew);
        rs += p;
        pk[r] = (bf16)p;
      }
      // P[q=l15][kv=rt*16+l4*4 .. +3], swizzled row q
      const int slot = (rt << 1) + (l4 >> 1);
      *(bf16x4*)(&Ps[w][l15 * 64 + ((slot ^ (l15 & 7)) << 3) + ((l4 & 1) << 2)]) = pk;
    }
    rs += __shfl_xor(rs, 16);
    rs += __shfl_xor(rs, 32);
    lrun = lrun * alpha + rs;
    mrun = mnew;
    // rescale o (o-frag rows are q = l4*4+r; alpha lives at lane q)
    float av[4];
#pragma unroll
    for (int r = 0; r < 4; ++r) av[r] = __shfl(alpha, (l4 << 2) + r);
#pragma unroll
    for (int di = 0; di < 4; ++di)
#pragma unroll
      for (int r = 0; r < 4; ++r) oacc[di][r] *= av[r];
    // PV: o[q][d] += P[q][kv] * V[kv][d]
    bf16x8 pa[2];
#pragma unroll
    for (int kk = 0; kk < 2; ++kk)
      pa[kk] = *(const bf16x8*)(&Ps[w][l15 * 64 +
                                       ((((kk << 2) + l4) ^ (l15 & 7)) << 3)]);
#pragma unroll
    for (int di = 0; di < 4; ++di) {
      const int row = di * 16 + l15;
      const bf16x8 v0 = *(const bf16x8*)(&Vs[row * 64 + ((l4 ^ (row & 7)) << 3)]);
      const bf16x8 v1 =
          *(const bf16x8*)(&Vs[row * 64 + (((4 + l4) ^ (row & 7)) << 3)]);
      oacc[di] = __builtin_amdgcn_mfma_f32_16x16x32_bf16(pa[0], v0, oacc[di], 0, 0, 0);
      oacc[di] = __builtin_amdgcn_mfma_f32_16x16x32_bf16(pa[1], v1, oacc[di], 0, 0, 0);
    }
  }
  float linv[4];
#pragma unroll
  for (int r = 0; r < 4; ++r) linv[r] = 1.f / __shfl(lrun, (l4 << 2) + r);
  const int b = bh >> 3, h = bh & 7;
  bf16* Op = og + (size_t)(b * NS + q0 + w * 16) * NC + h * ND;
#pragma unroll
  for (int di = 0; di < 4; ++di)
#pragma unroll
    for (int r = 0; r < 4; ++r)
      Op[(size_t)((l4 << 2) + r) * NC + di * 16 + l15] =
          (bf16)(oacc[di][r] * linv[r]);
}

// ---------------- 6) out GEMM: out[b][cout][s] = sum_k wo[cout,k]*o[(b,s),k] + bo
// A = wo (M=512=cout), B = o (N=8192=(b,s)) so stores coalesce along s.
__global__ __launch_bounds__(256) void gemm_out_kernel(
    const bf16* __restrict__ wob, const bf16* __restrict__ o,
    const float* __restrict__ bo, float* __restrict__ out) {
  __shared__ __align__(16) bf16 As[128 * 32];
  __shared__ __align__(16) bf16 Bs[128 * 32];
  const int tid = threadIdx.x;
  const int m0 = blockIdx.x * 128, n0 = blockIdx.y * 128;
  const int w = tid >> 6, lane = tid & 63, l15 = lane & 15, l4 = lane >> 4;
  const int wm = (w >> 1) << 6, wn = (w & 1) << 6;
  f32x4 acc[4][4] = {};
  for (int k0 = 0; k0 < 512; k0 += 32) {
    __syncthreads();
#pragma unroll
    for (int i = 0; i < 2; ++i) {
      const int c = i * 256 + tid, row = c >> 2, slot = c & 3;
      const int ds = (slot ^ ((row >> 1) & 3)) << 3;
      *(int4*)(&As[row * 32 + ds]) =
          *(const int4*)(&wob[(size_t)(m0 + row) * 512 + k0 + slot * 8]);
      *(int4*)(&Bs[row * 32 + ds]) =
          *(const int4*)(&o[(size_t)(n0 + row) * 512 + k0 + slot * 8]);
    }
    __syncthreads();
    bf16x8 af[4], bfv[4];
#pragma unroll
    for (int mi = 0; mi < 4; ++mi) {
      const int row = wm + mi * 16 + l15;
      af[mi] = *(const bf16x8*)(&As[row * 32 + ((l4 ^ ((row >> 1) & 3)) << 3)]);
    }
#pragma unroll
    for (int ni = 0; ni < 4; ++ni) {
      const int row = wn + ni * 16 + l15;
      bfv[ni] = *(const bf16x8*)(&Bs[row * 32 + ((l4 ^ ((row >> 1) & 3)) << 3)]);
    }
#pragma unroll
    for (int mi = 0; mi < 4; ++mi)
#pragma unroll
      for (int ni = 0; ni < 4; ++ni)
        acc[mi][ni] = __builtin_amdgcn_mfma_f32_16x16x32_bf16(af[mi], bfv[ni],
                                                              acc[mi][ni], 0, 0, 0);
  }
  const int b = n0 >> 10;
  const int sb = (n0 & 1023) + wn;
#pragma unroll
  for (int mi = 0; mi < 4; ++mi) {
#pragma unroll
    for (int r = 0; r < 4; ++r) {
      const int cout = m0 + wm + mi * 16 + (l4 << 2) + r;
      const float bsv = bo[cout];
#pragma unroll
      for (int ni = 0; ni < 4; ++ni)
        out[(size_t)(b * NC + cout) * NS + sb + ni * 16 + l15] =
            acc[mi][ni][r] + bsv;
    }
  }
}

// ---------------- launcher --------------------------------------------------
extern "C" void kernel_launch(void* const* d_in, const int* in_sizes, int n_in,
                              void* d_out, int out_size, void* d_ws,
                              size_t ws_size, hipStream_t stream) {
  const float* x = (const float*)d_in[0];
  const float* gam = (const float*)d_in[1];
  const float* bet = (const float*)d_in[2];
  const float* mu = (const float*)d_in[3];
  const float* var = (const float*)d_in[4];
  const float* wq = (const float*)d_in[5];
  const float* bq = (const float*)d_in[6];
  const float* wk = (const float*)d_in[7];
  const float* bk = (const float*)d_in[8];
  const float* wv = (const float*)d_in[9];
  const float* bv = (const float*)d_in[10];
  const float* wo = (const float*)d_in[11];
  const float* bo = (const float*)d_in[12];
  float* out = (float*)d_out;

  char* p = (char*)d_ws;
  const size_t big = (size_t)8192 * 512 * sizeof(bf16);  // 8.39 MB
  bf16* t = (bf16*)p;   p += big;  // reused as attention output o
  bf16* q = (bf16*)p;   p += big;
  bf16* k = (bf16*)p;   p += big;
  bf16* v = (bf16*)p;   p += big;
  bf16* vt = (bf16*)p;  p += big;
  const size_t wsz = (size_t)512 * 512 * sizeof(bf16);
  bf16* wqb = (bf16*)p; p += wsz;
  bf16* wkb = (bf16*)p; p += wsz;
  bf16* wvb = (bf16*)p; p += wsz;
  bf16* wob = (bf16*)p; p += wsz;
  bf16* o = t;

  bn_tr_kernel<<<dim3(32, 16, 8), 256, 0, stream>>>(x, gam, bet, mu, var, t);
  wconv_kernel<<<dim3(1024), 256, 0, stream>>>(wq, wk, wv, wo, wqb, wkb, wvb, wob);
  gemm_qkv_kernel<<<dim3(64, 12), 256, 0, stream>>>(t, wqb, wkb, wvb, bq, bk, bv,
                                                    q, k, v);
  vtr_kernel<<<dim3(16, 64), 256, 0, stream>>>(v, vt);
  attn_kernel<<<dim3(16, 64), 256, 0, stream>>>(q, k, vt, o);
  gemm_out_kernel<<<dim3(4, 64), 256, 0, stream>>>(wob, o, bo, out);
}

// Round 2
// 85.703 us; speedup vs baseline: 1.1458x; 1.1458x over previous
//
#include <hip/hip_runtime.h>
#include <stdint.h>

typedef __bf16 bf16;
typedef bf16 bf16x8 __attribute__((ext_vector_type(8)));
typedef bf16 bf16x4 __attribute__((ext_vector_type(4)));
typedef float f32x4 __attribute__((ext_vector_type(4)));

#define NB 8
#define NS 1024
#define NC 512
#define NH 8
#define ND 64

// q pre-scale: dim_head^-0.5 * log2(e) so attention uses exp2 directly
#define QSCALE 0.18033688011f

__device__ __forceinline__ void gload16(const void* g, void* l) {
  __builtin_amdgcn_global_load_lds(
      (const __attribute__((address_space(1))) void*)g,
      (__attribute__((address_space(3))) void*)l, 16, 0, 0);
}

// ---------------- 1) BN(eval) + transpose: x[b][c][s] -> t[b][s][c] bf16 ----
__global__ __launch_bounds__(256) void bn_tr_kernel(
    const float* __restrict__ x, const float* __restrict__ gam,
    const float* __restrict__ bet, const float* __restrict__ mu,
    const float* __restrict__ var, bf16* __restrict__ t) {
  __shared__ float tile[32][33];
  const int b = blockIdx.z, c0 = blockIdx.y * 32, s0 = blockIdx.x * 32;
  const int tx = threadIdx.x, sj = tx & 31, ci = tx >> 5;
#pragma unroll
  for (int kk = 0; kk < 4; ++kk) {
    const int c = c0 + ci + (kk << 3);
    const float sc = gam[c] * rsqrtf(var[c] + 1e-5f);
    const float sh = bet[c] - mu[c] * sc;
    tile[ci + (kk << 3)][sj] = x[(size_t)(b * NC + c) * NS + s0 + sj] * sc + sh;
  }
  __syncthreads();
#pragma unroll
  for (int kk = 0; kk < 4; ++kk) {
    const int s = s0 + ci + (kk << 3);
    t[(size_t)(b * NS + s) * NC + c0 + sj] = (bf16)tile[sj][ci + (kk << 3)];
  }
}

// ---------------- 2) weights f32 -> bf16 (vectorized) -----------------------
__global__ __launch_bounds__(256) void wconv_kernel(
    const float* __restrict__ wq, const float* __restrict__ wk,
    const float* __restrict__ wv, const float* __restrict__ wo,
    bf16* __restrict__ wqb, bf16* __restrict__ wkb, bf16* __restrict__ wvb,
    bf16* __restrict__ wob) {
  const int i = (blockIdx.x * 256 + threadIdx.x) * 4;
  float4 a = *(const float4*)(&wq[i]);
  float4 b = *(const float4*)(&wk[i]);
  float4 c = *(const float4*)(&wv[i]);
  float4 d = *(const float4*)(&wo[i]);
  bf16x4 av = {(bf16)a.x, (bf16)a.y, (bf16)a.z, (bf16)a.w};
  bf16x4 bv = {(bf16)b.x, (bf16)b.y, (bf16)b.z, (bf16)b.w};
  bf16x4 cv = {(bf16)c.x, (bf16)c.y, (bf16)c.z, (bf16)c.w};
  bf16x4 dv = {(bf16)d.x, (bf16)d.y, (bf16)d.z, (bf16)d.w};
  *(bf16x4*)(&wqb[i]) = av;
  *(bf16x4*)(&wkb[i]) = bv;
  *(bf16x4*)(&wvb[i]) = cv;
  *(bf16x4*)(&wob[i]) = dv;
}

// ---------------- 3) QKV GEMM: C[m,n] = sum_k t[m,k]*W[n,k] + b[n] ----------
// m = (b,s) over 8192, n = 0..1535 picks {wq,wk,wv}; q,k out [B][H][S][D],
// v out DIRECTLY TRANSPOSED [B][H][D][S].
__global__ __launch_bounds__(256) void gemm_qkv_kernel(
    const bf16* __restrict__ t, const bf16* __restrict__ wqb,
    const bf16* __restrict__ wkb, const bf16* __restrict__ wvb,
    const float* __restrict__ bq, const float* __restrict__ bk,
    const float* __restrict__ bv, bf16* __restrict__ qo, bf16* __restrict__ ko,
    bf16* __restrict__ vo) {
  __shared__ __align__(16) bf16 As[128 * 32];
  __shared__ __align__(16) bf16 Bs[128 * 32];
  const int tid = threadIdx.x;
  const int m0 = blockIdx.x * 128, n0 = blockIdx.y * 128;
  const int wsel = n0 >> 9;
  const bf16* W = (wsel == 0) ? wqb : (wsel == 1 ? wkb : wvb);
  const float* bias = (wsel == 0) ? bq : (wsel == 1 ? bk : bv);
  const int nb = n0 & 511;
  const int w = tid >> 6, lane = tid & 63, l15 = lane & 15, l4 = lane >> 4;
  const int wm = (w >> 1) << 6, wn = (w & 1) << 6;

  // staging geometry: linear LDS dest, inverse-swizzled global source
  const int srl = lane >> 2, sp = lane & 3;
  const int r0 = w * 16 + srl, r1 = 64 + w * 16 + srl;
  const int c0off = (sp ^ ((r0 >> 1) & 3)) << 3;
  const int c1off = (sp ^ ((r1 >> 1) & 3)) << 3;
  const bf16* a0 = t + (size_t)(m0 + r0) * 512 + c0off;
  const bf16* a1 = t + (size_t)(m0 + r1) * 512 + c1off;
  const bf16* b0 = W + (size_t)(nb + r0) * 512 + c0off;
  const bf16* b1 = W + (size_t)(nb + r1) * 512 + c1off;

  f32x4 acc[4][4] = {};
  for (int k0 = 0; k0 < 512; k0 += 32) {
    __syncthreads();
    gload16(a0 + k0, &As[w * 512]);
    gload16(a1 + k0, &As[2048 + w * 512]);
    gload16(b0 + k0, &Bs[w * 512]);
    gload16(b1 + k0, &Bs[2048 + w * 512]);
    __syncthreads();
    bf16x8 af[4], bfv[4];
#pragma unroll
    for (int mi = 0; mi < 4; ++mi) {
      const int row = wm + mi * 16 + l15;
      af[mi] = *(const bf16x8*)(&As[row * 32 + ((l4 ^ ((row >> 1) & 3)) << 3)]);
    }
#pragma unroll
    for (int ni = 0; ni < 4; ++ni) {
      const int row = wn + ni * 16 + l15;
      bfv[ni] = *(const bf16x8*)(&Bs[row * 32 + ((l4 ^ ((row >> 1) & 3)) << 3)]);
    }
#pragma unroll
    for (int mi = 0; mi < 4; ++mi)
#pragma unroll
      for (int ni = 0; ni < 4; ++ni)
        acc[mi][ni] = __builtin_amdgcn_mfma_f32_16x16x32_bf16(af[mi], bfv[ni],
                                                              acc[mi][ni], 0, 0, 0);
  }
  const int bidx = m0 >> 10;
  const int sbase = (m0 & 1023) + wm + (l4 << 2);
  if (wsel == 2) {
    // V: write transposed vt[bh][d][s], packed 4-consecutive-s stores
#pragma unroll
    for (int ni = 0; ni < 4; ++ni) {
      const int nn = nb + wn + ni * 16 + l15;
      const int hh = nn >> 6, dd = nn & 63;
      const float bsv = bias[nn];
      bf16* vbase = vo + (size_t)(bidx * NH + hh) * (ND * NS) + (size_t)dd * NS + sbase;
#pragma unroll
      for (int mi = 0; mi < 4; ++mi) {
        bf16x4 pk;
#pragma unroll
        for (int r = 0; r < 4; ++r) pk[r] = (bf16)(acc[mi][ni][r] + bsv);
        *(bf16x4*)(&vbase[mi * 16]) = pk;
      }
    }
  } else {
    const bool isq = (wsel == 0);
    bf16* outp = isq ? qo : ko;
#pragma unroll
    for (int ni = 0; ni < 4; ++ni) {
      const int nn = nb + wn + ni * 16 + l15;
      const int hh = nn >> 6, dd = nn & 63;
      const float bsv = bias[nn];
      bf16* obase = outp + (size_t)(bidx * NH + hh) * (NS * ND) + dd;
#pragma unroll
      for (int mi = 0; mi < 4; ++mi) {
#pragma unroll
        for (int r = 0; r < 4; ++r) {
          float val = acc[mi][ni][r] + bsv;
          if (isq) val *= QSCALE;
          obase[(size_t)(sbase + mi * 16 + r) * ND] = (bf16)val;
        }
      }
    }
  }
}

// ---------------- 4) flash attention ----------------------------------------
// grid (S/128, B*H), 8 waves; wave w owns q-rows [w*16, w*16+16).
// K/V double-buffered via global_load_lds (pre-swizzled source, swizzled read).
__global__ __launch_bounds__(512) void attn_kernel(const bf16* __restrict__ qg,
                                                   const bf16* __restrict__ kg,
                                                   const bf16* __restrict__ vtg,
                                                   bf16* __restrict__ og) {
  __shared__ __align__(16) bf16 Kb[2][64 * 64];
  __shared__ __align__(16) bf16 Vb[2][64 * 64];
  __shared__ __align__(16) bf16 Ps[8][16 * 64];
  const int bh = blockIdx.y, q0 = blockIdx.x * 128;
  const int tid = threadIdx.x, w = tid >> 6, lane = tid & 63;
  const int l15 = lane & 15, l4 = lane >> 4;
  const bf16* Qp = qg + ((size_t)bh * NS + q0) * ND;
  const bf16* Kp = kg + (size_t)bh * NS * ND;
  const bf16* Vp = vtg + (size_t)bh * ND * NS;

  // Q frags straight from global (no LDS)
  bf16x8 qf[2];
#pragma unroll
  for (int kk = 0; kk < 2; ++kk)
    qf[kk] = *(const bf16x8*)(&Qp[(size_t)(w * 16 + l15) * ND + ((kk << 2) + l4) * 8]);

  // staging lane geometry: wave w stages rows [w*8, w*8+8) of K and of V
  const int srow = w * 8 + (lane >> 3);
  const int soff = ((lane & 7) ^ (srow & 7)) << 3;
  const bf16* ksrc = Kp + (size_t)srow * ND + soff;   // + kv0*ND per tile
  const bf16* vsrc = Vp + (size_t)srow * NS + soff;   // + kv0 per tile

  // fragment read offsets (element units), same for K and V tiles
  int foff[4][2];
#pragma unroll
  for (int rt = 0; rt < 4; ++rt) {
    const int row = rt * 16 + l15;
    foff[rt][0] = row * 64 + ((l4 ^ (row & 7)) << 3);
    foff[rt][1] = row * 64 + (((4 + l4) ^ (row & 7)) << 3);
  }

  f32x4 oacc[4] = {};
  float mrun = -1e30f, lrun = 0.f;

  // prologue: stage tile 0 into buf 0
  gload16(ksrc, &Kb[0][w * 512]);
  gload16(vsrc, &Vb[0][w * 512]);
  __syncthreads();

  int buf = 0;
  for (int kv0 = 0; kv0 < NS; kv0 += 64, buf ^= 1) {
    // issue next-tile stage early; latency hides under this tile's compute
    if (kv0 + 64 < NS) {
      gload16(ksrc + (size_t)(kv0 + 64) * ND, &Kb[buf ^ 1][w * 512]);
      gload16(vsrc + (kv0 + 64), &Vb[buf ^ 1][w * 512]);
    }
    const bf16* Ks = Kb[buf];
    const bf16* Vs = Vb[buf];
    // S^T tiles: st[rt][r] = score(kv = rt*16 + l4*4 + r, q = l15)
    f32x4 st[4];
#pragma unroll
    for (int rt = 0; rt < 4; ++rt) {
      const bf16x8 a0 = *(const bf16x8*)(&Ks[foff[rt][0]]);
      const bf16x8 a1 = *(const bf16x8*)(&Ks[foff[rt][1]]);
      f32x4 z = {0.f, 0.f, 0.f, 0.f};
      z = __builtin_amdgcn_mfma_f32_16x16x32_bf16(a0, qf[0], z, 0, 0, 0);
      st[rt] = __builtin_amdgcn_mfma_f32_16x16x32_bf16(a1, qf[1], z, 0, 0, 0);
    }
    // online softmax for q-row l15
    float pm = -1e30f;
#pragma unroll
    for (int rt = 0; rt < 4; ++rt)
#pragma unroll
      for (int r = 0; r < 4; ++r) pm = fmaxf(pm, st[rt][r]);
    pm = fmaxf(pm, __shfl_xor(pm, 16));
    pm = fmaxf(pm, __shfl_xor(pm, 32));
    // defer-max (T13): skip rescale while growth <= 8 (log2 domain, P <= 256)
    if (!__all(pm - mrun <= 8.f)) {
      const float mnew = fmaxf(mrun, pm);
      const float alpha = __builtin_amdgcn_exp2f(mrun - mnew);
      float av[4];
#pragma unroll
      for (int r = 0; r < 4; ++r) av[r] = __shfl(alpha, (l4 << 2) + r);
#pragma unroll
      for (int di = 0; di < 4; ++di)
#pragma unroll
        for (int r = 0; r < 4; ++r) oacc[di][r] *= av[r];
      lrun *= alpha;
      mrun = mnew;
    }
    float rs = 0.f;
#pragma unroll
    for (int rt = 0; rt < 4; ++rt) {
      bf16x4 pk;
#pragma unroll
      for (int r = 0; r < 4; ++r) {
        const float p = __builtin_amdgcn_exp2f(st[rt][r] - mrun);
        rs += p;
        pk[r] = (bf16)p;
      }
      const int slot = (rt << 1) + (l4 >> 1);
      *(bf16x4*)(&Ps[w][l15 * 64 + ((slot ^ (l15 & 7)) << 3) + ((l4 & 1) << 2)]) = pk;
    }
    rs += __shfl_xor(rs, 16);
    rs += __shfl_xor(rs, 32);
    lrun += rs;
    // PV: o[q][d] += P[q][kv] * V[kv][d]
    bf16x8 pa[2];
#pragma unroll
    for (int kk = 0; kk < 2; ++kk)
      pa[kk] = *(const bf16x8*)(&Ps[w][l15 * 64 +
                                       ((((kk << 2) + l4) ^ (l15 & 7)) << 3)]);
#pragma unroll
    for (int di = 0; di < 4; ++di) {
      const bf16x8 v0 = *(const bf16x8*)(&Vs[foff[di][0]]);
      const bf16x8 v1 = *(const bf16x8*)(&Vs[foff[di][1]]);
      oacc[di] = __builtin_amdgcn_mfma_f32_16x16x32_bf16(pa[0], v0, oacc[di], 0, 0, 0);
      oacc[di] = __builtin_amdgcn_mfma_f32_16x16x32_bf16(pa[1], v1, oacc[di], 0, 0, 0);
    }
    __syncthreads();  // drains next-tile loads + protects buffer swap
  }
  float linv[4];
#pragma unroll
  for (int r = 0; r < 4; ++r) linv[r] = 1.f / __shfl(lrun, (l4 << 2) + r);
  const int b = bh >> 3, h = bh & 7;
  bf16* Op = og + (size_t)(b * NS + q0 + w * 16) * NC + h * ND;
#pragma unroll
  for (int di = 0; di < 4; ++di)
#pragma unroll
    for (int r = 0; r < 4; ++r)
      Op[(size_t)((l4 << 2) + r) * NC + di * 16 + l15] =
          (bf16)(oacc[di][r] * linv[r]);
}

// ---------------- 5) out GEMM: out[b][cout][s] = sum_k wo[cout,k]*o[(b,s),k] + bo
__global__ __launch_bounds__(256) void gemm_out_kernel(
    const bf16* __restrict__ wob, const bf16* __restrict__ o,
    const float* __restrict__ bo, float* __restrict__ out) {
  __shared__ __align__(16) bf16 As[128 * 32];
  __shared__ __align__(16) bf16 Bs[128 * 32];
  const int tid = threadIdx.x;
  const int m0 = blockIdx.x * 128, n0 = blockIdx.y * 128;
  const int w = tid >> 6, lane = tid & 63, l15 = lane & 15, l4 = lane >> 4;
  const int wm = (w >> 1) << 6, wn = (w & 1) << 6;

  const int srl = lane >> 2, sp = lane & 3;
  const int r0 = w * 16 + srl, r1 = 64 + w * 16 + srl;
  const int c0off = (sp ^ ((r0 >> 1) & 3)) << 3;
  const int c1off = (sp ^ ((r1 >> 1) & 3)) << 3;
  const bf16* a0 = wob + (size_t)(m0 + r0) * 512 + c0off;
  const bf16* a1 = wob + (size_t)(m0 + r1) * 512 + c1off;
  const bf16* b0 = o + (size_t)(n0 + r0) * 512 + c0off;
  const bf16* b1 = o + (size_t)(n0 + r1) * 512 + c1off;

  f32x4 acc[4][4] = {};
  for (int k0 = 0; k0 < 512; k0 += 32) {
    __syncthreads();
    gload16(a0 + k0, &As[w * 512]);
    gload16(a1 + k0, &As[2048 + w * 512]);
    gload16(b0 + k0, &Bs[w * 512]);
    gload16(b1 + k0, &Bs[2048 + w * 512]);
    __syncthreads();
    bf16x8 af[4], bfv[4];
#pragma unroll
    for (int mi = 0; mi < 4; ++mi) {
      const int row = wm + mi * 16 + l15;
      af[mi] = *(const bf16x8*)(&As[row * 32 + ((l4 ^ ((row >> 1) & 3)) << 3)]);
    }
#pragma unroll
    for (int ni = 0; ni < 4; ++ni) {
      const int row = wn + ni * 16 + l15;
      bfv[ni] = *(const bf16x8*)(&Bs[row * 32 + ((l4 ^ ((row >> 1) & 3)) << 3)]);
    }
#pragma unroll
    for (int mi = 0; mi < 4; ++mi)
#pragma unroll
      for (int ni = 0; ni < 4; ++ni)
        acc[mi][ni] = __builtin_amdgcn_mfma_f32_16x16x32_bf16(af[mi], bfv[ni],
                                                              acc[mi][ni], 0, 0, 0);
  }
  const int b = n0 >> 10;
  const int sb = (n0 & 1023) + wn;
#pragma unroll
  for (int mi = 0; mi < 4; ++mi) {
#pragma unroll
    for (int r = 0; r < 4; ++r) {
      const int cout = m0 + wm + mi * 16 + (l4 << 2) + r;
      const float bsv = bo[cout];
#pragma unroll
      for (int ni = 0; ni < 4; ++ni)
        out[(size_t)(b * NC + cout) * NS + sb + ni * 16 + l15] =
            acc[mi][ni][r] + bsv;
    }
  }
}

// ---------------- launcher --------------------------------------------------
extern "C" void kernel_launch(void* const* d_in, const int* in_sizes, int n_in,
                              void* d_out, int out_size, void* d_ws,
                              size_t ws_size, hipStream_t stream) {
  const float* x = (const float*)d_in[0];
  const float* gam = (const float*)d_in[1];
  const float* bet = (const float*)d_in[2];
  const float* mu = (const float*)d_in[3];
  const float* var = (const float*)d_in[4];
  const float* wq = (const float*)d_in[5];
  const float* bq = (const float*)d_in[6];
  const float* wk = (const float*)d_in[7];
  const float* bk = (const float*)d_in[8];
  const float* wv = (const float*)d_in[9];
  const float* bv = (const float*)d_in[10];
  const float* wo = (const float*)d_in[11];
  const float* bo = (const float*)d_in[12];
  float* out = (float*)d_out;

  char* p = (char*)d_ws;
  const size_t big = (size_t)8192 * 512 * sizeof(bf16);  // 8.39 MB
  bf16* t = (bf16*)p;   p += big;  // reused as attention output o
  bf16* q = (bf16*)p;   p += big;
  bf16* k = (bf16*)p;   p += big;
  bf16* vt = (bf16*)p;  p += big;  // V already transposed [B][H][D][S]
  const size_t wsz = (size_t)512 * 512 * sizeof(bf16);
  bf16* wqb = (bf16*)p; p += wsz;
  bf16* wkb = (bf16*)p; p += wsz;
  bf16* wvb = (bf16*)p; p += wsz;
  bf16* wob = (bf16*)p; p += wsz;
  bf16* o = t;

  bn_tr_kernel<<<dim3(32, 16, 8), 256, 0, stream>>>(x, gam, bet, mu, var, t);
  wconv_kernel<<<dim3(256), 256, 0, stream>>>(wq, wk, wv, wo, wqb, wkb, wvb, wob);
  gemm_qkv_kernel<<<dim3(64, 12), 256, 0, stream>>>(t, wqb, wkb, wvb, bq, bk, bv,
                                                    q, k, vt);
  attn_kernel<<<dim3(8, 64), 512, 0, stream>>>(q, k, vt, o);
  gemm_out_kernel<<<dim3(4, 64), 256, 0, stream>>>(wob, o, bo, out);
}